// Round 13
// baseline (5006.429 us; speedup 1.0000x reference)
//
#include <hip/hip_runtime.h>

#define B_   256
#define T_   512
#define DIN_ 128
#define H_   512
#define G4_  2048

typedef __bf16 bf16_t;
typedef __bf16 bf16x8 __attribute__((ext_vector_type(8)));
typedef __bf16 bf16x4 __attribute__((ext_vector_type(4)));
typedef float  f32x4  __attribute__((ext_vector_type(4)));
typedef float  f32x16 __attribute__((ext_vector_type(16)));

// coherent-point read (sc0|sc1 = 1|16): bypass L1+L2, read the MALL
__device__ __forceinline__ void gload16cc(const void* g, void* l) {
  __builtin_amdgcn_global_load_lds(
      (const __attribute__((address_space(1))) unsigned int*)g,
      (__attribute__((address_space(3))) unsigned int*)l, 16, 0, 17);
}
__device__ __forceinline__ int fload(const int* p) {
  return __hip_atomic_load(p, __ATOMIC_RELAXED, __HIP_MEMORY_SCOPE_AGENT);
}

// ---------------- prep ----------------
__global__ void cast_f32_bf16(const float* __restrict__ s, bf16_t* __restrict__ d, int n) {
  int i = (blockIdx.x * 256 + threadIdx.x) * 4;
  if (i >= n) return;
  float4 v = *(const float4*)(s + i);
  bf16x4 o;
  o[0] = (bf16_t)v.x; o[1] = (bf16_t)v.y; o[2] = (bf16_t)v.z; o[3] = (bf16_t)v.w;
  *(bf16x4*)(d + i) = o;
}

__global__ void cast_strided(const float* __restrict__ s, bf16_t* __restrict__ d,
                             int Ks, int Kd, int coff) {
  int npr = Ks >> 3;
  int i = blockIdx.x * 256 + threadIdx.x;
  if (i >= 2048 * npr) return;
  int row = i / npr, j = i - row * npr;
  const float* sp = s + (size_t)row * Ks + j * 8;
  float4 v0 = *(const float4*)sp;
  float4 v1 = *(const float4*)(sp + 4);
  bf16x8 o;
  o[0] = (bf16_t)v0.x; o[1] = (bf16_t)v0.y; o[2] = (bf16_t)v0.z; o[3] = (bf16_t)v0.w;
  o[4] = (bf16_t)v1.x; o[5] = (bf16_t)v1.y; o[6] = (bf16_t)v1.z; o[7] = (bf16_t)v1.w;
  *(bf16x8*)(d + (size_t)row * Kd + coff + j * 8) = o;
}

__global__ void bias_sum(const float* __restrict__ a, const float* __restrict__ b,
                         float* __restrict__ o, int n) {
  int i = blockIdx.x * 256 + threadIdx.x;
  if (i < n) o[i] = a[i] + b[i];
}

// ---------------- persistent 3-layer LSTM, fully stage-symmetric -----------
// 256 blocks = 192 mains (3 layers x 4bg x 16ug, ALL H-only now) + 64 helpers
// (2hl x 4bg x 8ng). Helpers: xg_hl(s) = h_{hl-1}(s)@W_ih_hl^T AND (waves 4-7)
// xg0(s+8) = x(s+8)@W_ih0^T into a 16-slot ring (x static -> 8-step lead,
// 8-iter prologue). All waits resolve to strictly earlier events.
#define RING_N  (8 * 256 * 512)
#define XG_N    (8 * 256 * 2048)
#define XG0_N   (16 * 256 * 2048)
#define FSTR    16

// ============ mains: H-part only (K=512), xg from ring =====================
template<int LAYER>
__device__ __forceinline__ void main_loop(
    char* smem, const bf16_t* __restrict__ wcl, const float* __restrict__ bias_l,
    const float* __restrict__ xgRing, bf16_t* ringOwn, float* __restrict__ hsf,
    int* flags, int* xgf, int* xgf0, int bg, int ug)
{
  constexpr int KLW   = LAYER ? 1024 : 640;  // W row stride
  constexpr int WOFF  = LAYER ? 512 : 128;   // hh column offset
  constexpr int XMASK = LAYER ? 7 : 15;      // xg ring slots - 1
  constexpr int XTH   = LAYER ? 8 : 16;      // xg flag threshold
  const int tid  = threadIdx.x;
  const int lane = tid & 63;
  const int wv   = tid >> 6;
  const int g    = wv & 3;
  const int kh   = wv >> 2;
  const int r32  = lane & 31;
  const int l5   = lane >> 5;
  const int u0   = ug * 32;

  bf16x8 wfrag[16];
  {
    const bf16_t* wrow = wcl + (size_t)(g * 512 + u0 + r32) * KLW + WOFF + kh * 256 + l5 * 8;
    #pragma unroll
    for (int i = 0; i < 16; ++i) wfrag[i] = *(const bf16x8*)(wrow + i * 16);
  }
  const int um = tid >> 3;
  const int uq = tid & 7;
  float bsv[4][4];
  #pragma unroll
  for (int g2 = 0; g2 < 4; ++g2)
    #pragma unroll
    for (int q = 0; q < 4; ++q)
      bsv[g2][q] = bias_l[g2 * 512 + u0 + uq * 4 + q];

  float cst[4] = {0.f, 0.f, 0.f, 0.f};

  int* fl_own = flags + ((LAYER * 512) * 4 + bg) * FSTR;
  int* xin    = (LAYER == 0) ? (xgf0 + bg * FSTR)
                             : (xgf + (((LAYER - 1) * 512) * 4 + bg) * FSTR);
  int* bp     = (LAYER == 0) ? (xgf + (0 * 4 + bg) * FSTR)          // helper1 xg1 done
              : (LAYER == 1) ? (xgf + ((1 * 512) * 4 + bg) * FSTR)  // helper2 xg2 done
              : (int*)nullptr;

  for (int s = 0; s < 512; ++s) {
    const int slot  = s & 7;
    const int slot2 = (s - 1) & 7;
    const int xslot = s & XMASK;
    if (tid == 0) {
      while (fload(xin + s * 4 * FSTR) < XTH) __builtin_amdgcn_s_sleep(1);
      if (s > 0)
        while (fload(fl_own + (s - 1) * 4 * FSTR) < 16) __builtin_amdgcn_s_sleep(1);
      if (LAYER < 2 && s >= 8)   // h-ring slot reuse: helper consumed s-8
        while (fload(bp + (s - 8) * 4 * FSTR) < 8) __builtin_amdgcn_s_sleep(1);
    }
    __syncthreads();                   // (c')
    // ---- DMA: own-h [64][512]bf16 -> smem[0..64K); xg slice -> [64K..96K)
    {
      const bf16_t* ownS = ringOwn + (size_t)slot2 * (256 * 512) + (size_t)(bg * 64) * 512;
      #pragma unroll
      for (int i = 0; i < 8; ++i) {
        int r = i * 8 + wv;
        gload16cc(ownS + r * 512 + (lane ^ (r & 15)) * 8, smem + r * 1024);
      }
      const float* xgS = xgRing + (size_t)xslot * (256 * 2048) + (size_t)(bg * 64) * 2048;
      #pragma unroll
      for (int i = 0; i < 4; ++i) {
        int id = (i * 8 + wv) * 64 + lane;       // 2048 chunks of 16B
        int row = id >> 5, sub = id & 31, g2 = sub >> 3, cp = sub & 7;
        gload16cc(xgS + (size_t)row * 2048 + g2 * 512 + u0 + cp * 4,
                  smem + 65536 + (i * 8 + wv) * 1024);
      }
    }
    __syncthreads();                   // (d) DMAs visible
    f32x16 acc0 = {}, acc1 = {};
    #pragma unroll
    for (int i = 0; i < 16; ++i) {     // H-MFMA (K=256 per kh-wave)
      const int c  = (kh * 16 + i) * 2 + l5;
      const int px = c ^ (r32 & 15);
      bf16x8 a0 = *(const bf16x8*)(smem + r32 * 1024 + px * 16);
      bf16x8 a1 = *(const bf16x8*)(smem + (32 + r32) * 1024 + px * 16);
      acc0 = __builtin_amdgcn_mfma_f32_32x32x16_bf16(a0, wfrag[i], acc0, 0, 0, 0);
      acc1 = __builtin_amdgcn_mfma_f32_32x32x16_bf16(a1, wfrag[i], acc1, 0, 0, 0);
    }
    __syncthreads();                   // (e) A-reads done: h region reusable
    {
      char* pb = smem + kh * 32768 + (g * 32 + r32) * 4;   // [kh][64m][128n] f32
      #pragma unroll
      for (int reg = 0; reg < 16; ++reg) {
        int mr = (reg & 3) + 8 * (reg >> 2) + 4 * l5;
        *(float*)(pb + mr * 512)        = acc0[reg];
        *(float*)(pb + (32 + mr) * 512) = acc1[reg];
      }
    }
    __syncthreads();                   // (f)
    union { bf16x4 v; unsigned long long u; } pk;
    f32x4 hvf;
    {
      const char* gpb = smem + um * 512;
      const char* xgb = smem + 65536 + um * 512;
      f32x4 gvv[4];
      #pragma unroll
      for (int g2 = 0; g2 < 4; ++g2) {
        f32x4 p0 = *(const f32x4*)(gpb + (g2 * 32 + uq * 4) * 4);
        f32x4 p1 = *(const f32x4*)(gpb + 32768 + (g2 * 32 + uq * 4) * 4);
        f32x4 xv = *(const f32x4*)(xgb + g2 * 128 + uq * 16);
        #pragma unroll
        for (int q = 0; q < 4; ++q) gvv[g2][q] = p0[q] + p1[q] + xv[q];
      }
      #pragma unroll
      for (int q = 0; q < 4; ++q) {
        float i_ = gvv[0][q] + bsv[0][q];
        float f_ = gvv[1][q] + bsv[1][q];
        float g_ = gvv[2][q] + bsv[2][q];
        float o_ = gvv[3][q] + bsv[3][q];
        float si = 1.f / (1.f + __expf(-i_));
        float sf = 1.f / (1.f + __expf(-f_));
        float so = 1.f / (1.f + __expf(-o_));
        float tg = 2.f / (1.f + __expf(-2.f * g_)) - 1.f;
        float cv = sf * cst[q] + si * tg;
        cst[q] = cv;
        float th = 2.f / (1.f + __expf(-2.f * cv)) - 1.f;
        hvf[q] = so * th;
        pk.v[q] = (bf16_t)hvf[q];
      }
    }
    {
      int b = bg * 64 + um;
      bf16_t* dst = ringOwn + (size_t)slot * (256 * 512) + (size_t)b * 512 + u0 + uq * 4;
      (void)__hip_atomic_exchange((unsigned long long*)dst, pk.u,
                                  __ATOMIC_RELAXED, __HIP_MEMORY_SCOPE_AGENT);
      if (LAYER == 2 && s == 511)
        *(f32x4*)(hsf + (size_t)b * 512 + u0 + uq * 4) = hvf;
    }
    __syncthreads();                   // (g) publishes acked at MALL
    if (tid == 0) atomicAdd(fl_own + s * 4 * FSTR, 1);
  }
}

// ============ helpers: xg_hl(s) (all waves) + xg0(s+8) (waves 4-7) =========
template<int HL>
__device__ __forceinline__ void helper_loop(
    char* smem, const bf16_t* __restrict__ wihl, const bf16_t* __restrict__ wc0,
    const bf16_t* __restrict__ xbf, const bf16_t* __restrict__ ringPrev,
    float* __restrict__ xgRing, float* __restrict__ xg0Ring,
    int* flags, int* xgf, int* xgf0, int bg, int ng)
{
  const int tid  = threadIdx.x;
  const int lane = tid & 63;
  const int wv   = tid >> 6;
  const int r32  = lane & 31;
  const int l5   = lane >> 5;
  const int n0   = ng * 256 + wv * 32;   // xg_hl: this wave's 32 gate-rows
  const int cs   = (HL - 1) * 8 + ng;    // xg0 col-slice [cs*128, cs*128+128)

  bf16x8 wfrag[32];                      // W_ih_hl rows n0+r32, K=512
  {
    const bf16_t* wrow = wihl + (size_t)(n0 + r32) * 1024 + l5 * 8;
    #pragma unroll
    for (int i = 0; i < 32; ++i) wfrag[i] = *(const bf16x8*)(wrow + i * 16);
  }
  int* fl_prev  = flags + (((HL - 1) * 512) * 4 + bg) * FSTR;  // h producer
  int* fl_cons  = flags + ((HL * 512) * 4 + bg) * FSTR;        // xg consumer mains
  int* xgf_own  = xgf + (((HL - 1) * 512) * 4 + bg) * FSTR;
  int* xgf0_own = xgf0 + bg * FSTR;

  for (int s = -8; s < 512; ++s) {
    const bool doH = (s >= 0);
    const bool doX = (s + 8 < 512);
    const int  slot = s & 7;
    if (doH && tid == 0) {
      while (fload(fl_prev + s * 4 * FSTR) < 16) __builtin_amdgcn_s_sleep(1);
      if (s >= 8)
        while (fload(fl_cons + (s - 8) * 4 * FSTR) < 16) __builtin_amdgcn_s_sleep(1);
    }
    __syncthreads();                   // B0
    if (doH) {
      const bf16_t* src = ringPrev + (size_t)slot * (256 * 512) + (size_t)(bg * 64) * 512;
      #pragma unroll
      for (int i = 0; i < 8; ++i) {
        int r = i * 8 + wv;
        gload16cc(src + r * 512 + (lane ^ (r & 15)) * 8, smem + r * 1024);
      }
    }
    if (doX) {                         // stage x(s+8): [64][128] bf16 @65536
      #pragma unroll
      for (int i2 = 0; i2 < 2; ++i2) {
        int id = i2 * 512 + tid, r = id >> 4, cx = id & 15;
        bf16x8 v = *(const bf16x8*)(xbf + ((size_t)(bg * 64 + r) * T_ + (s + 8)) * 128 + cx * 8);
        *(bf16x8*)(smem + 65536 + r * 256 + (cx ^ (r & 15)) * 16) = v;
      }
    }
    __syncthreads();                   // B1: h DMA + x stage visible
    if (doH) {
      f32x16 acc0 = {}, acc1 = {};
      #pragma unroll
      for (int i = 0; i < 32; ++i) {
        const int px = (i * 2 + l5) ^ (r32 & 15);
        bf16x8 a0 = *(const bf16x8*)(smem + r32 * 1024 + px * 16);
        bf16x8 a1 = *(const bf16x8*)(smem + (32 + r32) * 1024 + px * 16);
        acc0 = __builtin_amdgcn_mfma_f32_32x32x16_bf16(a0, wfrag[i], acc0, 0, 0, 0);
        acc1 = __builtin_amdgcn_mfma_f32_32x32x16_bf16(a1, wfrag[i], acc1, 0, 0, 0);
      }
      float* dst = xgRing + (size_t)slot * (256 * 2048) + (size_t)(bg * 64) * 2048 + n0 + r32;
      #pragma unroll
      for (int reg = 0; reg < 16; ++reg) {
        int mr = (reg & 3) + 8 * (reg >> 2) + 4 * l5;
        __hip_atomic_store(dst + (size_t)mr * 2048, acc0[reg],
                           __ATOMIC_RELAXED, __HIP_MEMORY_SCOPE_AGENT);
        __hip_atomic_store(dst + (size_t)(32 + mr) * 2048, acc1[reg],
                           __ATOMIC_RELAXED, __HIP_MEMORY_SCOPE_AGENT);
      }
    }
    if (doX && wv >= 4) {              // xg0(s+8): 64 rows x 32 cols, K=128
      bf16x8 wf0[8];
      const bf16_t* w0 = wc0 + (size_t)(cs * 128 + (wv - 4) * 32 + r32) * 640 + l5 * 8;
      #pragma unroll
      for (int t = 0; t < 8; ++t) wf0[t] = *(const bf16x8*)(w0 + t * 16);
      f32x16 x0 = {}, x1 = {};
      #pragma unroll
      for (int t = 0; t < 8; ++t) {
        const int px = (t * 2 + l5) ^ (r32 & 15);
        bf16x8 a0 = *(const bf16x8*)(smem + 65536 + r32 * 256 + px * 16);
        bf16x8 a1 = *(const bf16x8*)(smem + 65536 + (32 + r32) * 256 + px * 16);
        x0 = __builtin_amdgcn_mfma_f32_32x32x16_bf16(a0, wf0[t], x0, 0, 0, 0);
        x1 = __builtin_amdgcn_mfma_f32_32x32x16_bf16(a1, wf0[t], x1, 0, 0, 0);
      }
      float* dst0 = xg0Ring + (size_t)((s + 8) & 15) * (256 * 2048)
                  + (size_t)(bg * 64) * 2048 + cs * 128 + (wv - 4) * 32 + r32;
      #pragma unroll
      for (int reg = 0; reg < 16; ++reg) {
        int mr = (reg & 3) + 8 * (reg >> 2) + 4 * l5;
        __hip_atomic_store(dst0 + (size_t)mr * 2048, x0[reg],
                           __ATOMIC_RELAXED, __HIP_MEMORY_SCOPE_AGENT);
        __hip_atomic_store(dst0 + (size_t)(32 + mr) * 2048, x1[reg],
                           __ATOMIC_RELAXED, __HIP_MEMORY_SCOPE_AGENT);
      }
    }
    __syncthreads();                   // B2: all stores drained (vmcnt 0)
    if (tid == 0) {
      if (doH) atomicAdd(xgf_own + s * 4 * FSTR, 1);
      if (doX) atomicAdd(xgf0_own + (s + 8) * 4 * FSTR, 1);
    }
  }
}

__global__ __launch_bounds__(512, 2)
void lstm_persist(const bf16_t* __restrict__ xbf, const bf16_t* __restrict__ wc,
                  const float* __restrict__ bias, bf16_t* __restrict__ rings,
                  float* __restrict__ xg, float* __restrict__ xg0,
                  float* __restrict__ hsf, int* __restrict__ flags)
{
  __shared__ __align__(16) char smem[131072];
  int* xgf  = flags + 3 * 512 * 4 * FSTR;
  int* xgf0 = xgf + 2 * 512 * 4 * FSTR;
  const int bid = blockIdx.x;
  const bf16_t* wc1 = wc + 2048 * 640;
  const bf16_t* wc2 = wc1 + 2048 * 1024;
  if (bid < 192) {
    const int layer = bid >> 6;
    const int bg    = (bid >> 4) & 3;
    const int ug    = bid & 15;
    bf16_t* ringOwn = rings + (size_t)layer * RING_N;
    if (layer == 0)
      main_loop<0>(smem, wc,  bias,        xg0,        ringOwn, hsf, flags, xgf, xgf0, bg, ug);
    else if (layer == 1)
      main_loop<1>(smem, wc1, bias + 2048, xg,         ringOwn, hsf, flags, xgf, xgf0, bg, ug);
    else
      main_loop<2>(smem, wc2, bias + 4096, xg + XG_N,  ringOwn, hsf, flags, xgf, xgf0, bg, ug);
  } else {
    const int hid = bid - 192;
    const int hl  = 1 + (hid >> 5);
    const int bg  = (hid >> 3) & 3;
    const int ng  = hid & 7;
    const bf16_t* wihl = (hl == 1) ? wc1 : wc2;       // ih cols 0..511
    const bf16_t* ringPrev = rings + (size_t)(hl - 1) * RING_N;
    float* xgR = xg + (size_t)(hl - 1) * XG_N;
    if (hl == 1)
      helper_loop<1>(smem, wihl, wc, xbf, ringPrev, xgR, xg0, flags, xgf, xgf0, bg, ng);
    else
      helper_loop<2>(smem, wihl, wc, xbf, ringPrev, xgR, xg0, flags, xgf, xgf0, bg, ng);
  }
}

// ---------------- final FC ----------------
__global__ void fc_kernel(const float* __restrict__ h, const float* __restrict__ Wfc,
                          const float* __restrict__ bfc, float* __restrict__ out) {
  int b = blockIdx.x;
  int l = threadIdx.x;
  const float* hp = h + (size_t)b * H_;
  float acc = 0.f;
  #pragma unroll
  for (int i = 0; i < 8; ++i) acc += hp[l + i * 64] * Wfc[l + i * 64];
  #pragma unroll
  for (int off = 32; off; off >>= 1) acc += __shfl_down(acc, off, 64);
  if (l == 0) out[b] = acc + bfc[0];
}

// ---------------- host ----------------
extern "C" void kernel_launch(void* const* d_in, const int* in_sizes, int n_in,
                              void* d_out, int out_size, void* d_ws, size_t ws_size,
                              hipStream_t stream) {
  const float* x        = (const float*)d_in[0];
  const float* Wih_f[3] = {(const float*)d_in[1], (const float*)d_in[5], (const float*)d_in[9]};
  const float* Whh_f[3] = {(const float*)d_in[2], (const float*)d_in[6], (const float*)d_in[10]};
  const float* bih_f[3] = {(const float*)d_in[3], (const float*)d_in[7], (const float*)d_in[11]};
  const float* bhh_f[3] = {(const float*)d_in[4], (const float*)d_in[8], (const float*)d_in[12]};
  const float* Wfc = (const float*)d_in[13];
  const float* bfc = (const float*)d_in[14];

  const size_t FLAGS_BYTES = (size_t)(3 * 512 * 4 + 2 * 512 * 4 + 512 * 4) * FSTR * 4;

  char* ws = (char*)d_ws;
  size_t off = 0;
  auto take = [&](size_t bytes) { char* p = ws + off; off = (off + bytes + 255) & ~255ULL; return p; };
  bf16_t* XBF   = (bf16_t*)take((size_t)B_ * T_ * DIN_ * 2);           // 33.6 MB
  bf16_t* WC    = (bf16_t*)take((size_t)(2048*640 + 2*2048*1024) * 2); // 11.0 MB
  float*  BIAS  = (float*) take(3 * 2048 * 4);
  bf16_t* RINGS = (bf16_t*)take((size_t)3 * RING_N * 2);               // 6.3 MB
  float*  XG    = (float*) take((size_t)2 * XG_N * 4);                 // 33.6 MB
  float*  XG0   = (float*) take((size_t)XG0_N * 4);                    // 33.6 MB
  float*  HSF   = (float*) take((size_t)B_ * H_ * 4);
  int*    FLAGS = (int*)   take(FLAGS_BYTES);                          // 0.79 MB

  bf16_t* WC1 = WC + 2048 * 640;
  bf16_t* WC2 = WC1 + 2048 * 1024;

  cast_f32_bf16<<<16384, 256, 0, stream>>>(x, XBF, B_ * T_ * DIN_);
  cast_strided<<<128, 256, 0, stream>>>(Wih_f[0], WC,  128, 640, 0);
  cast_strided<<<512, 256, 0, stream>>>(Whh_f[0], WC,  512, 640, 128);
  cast_strided<<<512, 256, 0, stream>>>(Wih_f[1], WC1, 512, 1024, 0);
  cast_strided<<<512, 256, 0, stream>>>(Whh_f[1], WC1, 512, 1024, 512);
  cast_strided<<<512, 256, 0, stream>>>(Wih_f[2], WC2, 512, 1024, 0);
  cast_strided<<<512, 256, 0, stream>>>(Whh_f[2], WC2, 512, 1024, 512);
  for (int l = 0; l < 3; ++l)
    bias_sum<<<8, 256, 0, stream>>>(bih_f[l], bhh_f[l], BIAS + l * 2048, G4_);
  hipMemsetAsync(RINGS, 0, (size_t)3 * RING_N * 2, stream);
  hipMemsetAsync(FLAGS, 0, FLAGS_BYTES, stream);

  lstm_persist<<<256, 512, 0, stream>>>(XBF, WC, BIAS, RINGS, XG, XG0, HSF, FLAGS);
  fc_kernel<<<B_, 64, 0, stream>>>(HSF, Wfc, bfc, (float*)d_out);
}

// Round 14
// 3717.985 us; speedup vs baseline: 1.3465x; 1.3465x over previous
//
#include <hip/hip_runtime.h>

#define B_   256
#define T_   512
#define DIN_ 128
#define H_   512
#define G4_  2048

typedef __bf16 bf16_t;
typedef __bf16 bf16x8 __attribute__((ext_vector_type(8)));
typedef __bf16 bf16x4 __attribute__((ext_vector_type(4)));
typedef float  f32x4  __attribute__((ext_vector_type(4)));
typedef float  f32x16 __attribute__((ext_vector_type(16)));

// coherent-point read (sc0|sc1 = 1|16): bypass L1+L2, read the MALL
__device__ __forceinline__ void gload16cc(const void* g, void* l) {
  __builtin_amdgcn_global_load_lds(
      (const __attribute__((address_space(1))) unsigned int*)g,
      (__attribute__((address_space(3))) unsigned int*)l, 16, 0, 17);
}
__device__ __forceinline__ int fload(const int* p) {
  return __hip_atomic_load(p, __ATOMIC_RELAXED, __HIP_MEMORY_SCOPE_AGENT);
}

// ---------------- prep ----------------
__global__ void cast_f32_bf16(const float* __restrict__ s, bf16_t* __restrict__ d, int n) {
  int i = (blockIdx.x * 256 + threadIdx.x) * 4;
  if (i >= n) return;
  float4 v = *(const float4*)(s + i);
  bf16x4 o;
  o[0] = (bf16_t)v.x; o[1] = (bf16_t)v.y; o[2] = (bf16_t)v.z; o[3] = (bf16_t)v.w;
  *(bf16x4*)(d + i) = o;
}

// src f32 [2048][Ks] -> dst bf16 rows stride Kd at col offset coff
__global__ void cast_strided(const float* __restrict__ s, bf16_t* __restrict__ d,
                             int Ks, int Kd, int coff) {
  int npr = Ks >> 3;
  int i = blockIdx.x * 256 + threadIdx.x;
  if (i >= 2048 * npr) return;
  int row = i / npr, j = i - row * npr;
  const float* sp = s + (size_t)row * Ks + j * 8;
  float4 v0 = *(const float4*)sp;
  float4 v1 = *(const float4*)(sp + 4);
  bf16x8 o;
  o[0] = (bf16_t)v0.x; o[1] = (bf16_t)v0.y; o[2] = (bf16_t)v0.z; o[3] = (bf16_t)v0.w;
  o[4] = (bf16_t)v1.x; o[5] = (bf16_t)v1.y; o[6] = (bf16_t)v1.z; o[7] = (bf16_t)v1.w;
  *(bf16x8*)(d + (size_t)row * Kd + coff + j * 8) = o;
}

__global__ void bias_sum(const float* __restrict__ a, const float* __restrict__ b,
                         float* __restrict__ o, int n) {
  int i = blockIdx.x * 256 + threadIdx.x;
  if (i < n) o[i] = a[i] + b[i];
}

// ---------------- persistent 3-layer LSTM ----------------
// Round-10 structure (best, 3.27 ms). ONE change: wave-autonomous polls —
// each wave's lane0 polls fl_own(s-1)/fl_next(s-8), __shfl-broadcasts, and
// the wave issues its stage-H rows immediately. Barrier (c) deleted.
#define RING_N (8 * 256 * 512)
#define FSTR   16   // ints per flag (64B line)

template<bool L0>
__device__ __forceinline__ void step_loop(
    char* smem, const bf16_t* __restrict__ xbf, const bf16_t* __restrict__ wcl,
    const float* __restrict__ bias_l, bf16_t* ringPrev, bf16_t* ringOwn,
    float* __restrict__ hsf, int* flags, int layer, int bg, int ug)
{
  constexpr int KL   = L0 ? 640 : 1024;
  constexpr int ROWB = KL * 2;          // LDS row bytes
  constexpr int XT   = L0 ? 4 : 16;     // X-phase k-tiles(16) per wave
  constexpr int HT   = 16;              // H-phase k-tiles per wave
  constexpr int XP1  = L0 ? 2 : 8;      // X-MFMA tiles before stage-H issue
  constexpr int HOFF = L0 ? 256 : 1024; // byte offset of H region in a row
  const int tid  = threadIdx.x;
  const int lane = tid & 63;
  const int wv   = tid >> 6;
  const int g    = wv & 3;              // gate 0..3 (i,f,g,o)
  const int kh   = wv >> 2;             // K-half 0/1
  const int r32  = lane & 31;
  const int l5   = lane >> 5;
  const int u0   = ug * 32;
  const int t0x  = L0 ? (kh * 4) : (kh * 16);
  const int t0h  = L0 ? (8 + kh * 16) : (32 + kh * 16);

  // W fragments: lane holds W[g*512+u0+r32][tile*16 + l5*8 ..+8]
  bf16x8 wfrag[XT + HT];
  {
    const bf16_t* wrow = wcl + (size_t)(g * 512 + u0 + r32) * KL + l5 * 8;
    #pragma unroll
    for (int i = 0; i < XT; ++i) wfrag[i]      = *(const bf16x8*)(wrow + (t0x + i) * 16);
    #pragma unroll
    for (int i = 0; i < HT; ++i) wfrag[XT + i] = *(const bf16x8*)(wrow + (t0h + i) * 16);
  }
  const int um = tid >> 3;
  const int uq = tid & 7;
  float bsv[4][4];
  #pragma unroll
  for (int g2 = 0; g2 < 4; ++g2)
    #pragma unroll
    for (int q = 0; q < 4; ++q)
      bsv[g2][q] = bias_l[g2 * 512 + u0 + uq * 4 + q];

  float cst[4] = {0.f, 0.f, 0.f, 0.f};
  float* gp = (float*)smem;   // partials overlay: [2 kh][64 m][128 n] f32 = 64 KB

  int* fl_own  = flags + ((layer * 512) * 4 + bg) * FSTR;
  int* fl_prev = flags + (((layer - 1) * 512) * 4 + bg) * FSTR;
  int* fl_next = flags + (((layer + 1) * 512) * 4 + bg) * FSTR;

  for (int s = 0; s < 512; ++s) {
    const int slot  = s & 7;
    const int slot2 = (s - 1) & 7;
    // ================= Phase X: prev-layer input (no own-h dependency) =====
    if (!L0) {
      if (tid == 0)
        while (fload(fl_prev + s * 4 * FSTR) < 16) __builtin_amdgcn_s_sleep(1);
      __syncthreads();                 // (a) flag visible; gp reads of s-1 done
      const bf16_t* prvS = ringPrev + (size_t)slot * (256 * 512) + (size_t)(bg * 64) * 512;
      #pragma unroll
      for (int i = 0; i < 8; ++i) {    // X region: chunks 0..63
        int r = i * 8 + wv;
        gload16cc(prvS + r * 512 + (lane ^ (r & 15)) * 8, smem + r * ROWB);
      }
    } else {
      #pragma unroll
      for (int i2 = 0; i2 < 2; ++i2) { // x-part: chunks 0..15 via regs
        int idx = i2 * 512 + tid;
        int r = idx >> 4, cx = idx & 15;
        int px = cx ^ (r & 15);
        bf16x8 v = *(const bf16x8*)(xbf + ((size_t)(bg * 64 + r) * T_ + s) * 128 + cx * 8);
        *(bf16x8*)(smem + r * ROWB + px * 16) = v;
      }
    }
    __syncthreads();                   // (b) X staged
    f32x16 acc0 = {}, acc1 = {};
    // ---- X-MFMA part 1
    #pragma unroll
    for (int i = 0; i < XP1; ++i) {
      const int px = ((t0x + i) * 2 + l5) ^ (r32 & 15);
      bf16x8 a0 = *(const bf16x8*)(smem + r32 * ROWB + px * 16);
      bf16x8 a1 = *(const bf16x8*)(smem + (32 + r32) * ROWB + px * 16);
      acc0 = __builtin_amdgcn_mfma_f32_32x32x16_bf16(a0, wfrag[i], acc0, 0, 0, 0);
      acc1 = __builtin_amdgcn_mfma_f32_32x32x16_bf16(a1, wfrag[i], acc1, 0, 0, 0);
    }
    // ---- per-wave polls (replaces tid0 poll + (c) barrier)
    if (s > 0) {
      int ok = 0;
      do {
        int v = (lane == 0) ? fload(fl_own + (s - 1) * 4 * FSTR) : 0;
        ok = (__shfl(v, 0, 64) >= 16);
        if (!ok) __builtin_amdgcn_s_sleep(1);
      } while (!ok);
    }
    if (layer < 2 && s >= 8) {         // ring back-pressure (depth 8)
      int ok = 0;
      do {
        int v = (lane == 0) ? fload(fl_next + (s - 8) * 4 * FSTR) : 0;
        ok = (__shfl(v, 0, 64) >= 16);
        if (!ok) __builtin_amdgcn_s_sleep(1);
      } while (!ok);
    }
    // ---- stage-H issue (per wave, immediately after its own poll)
    {
      const bf16_t* ownS = ringOwn + (size_t)slot2 * (256 * 512) + (size_t)(bg * 64) * 512;
      #pragma unroll
      for (int i = 0; i < 8; ++i) {    // H region
        int r = i * 8 + wv;
        gload16cc(ownS + r * 512 + (lane ^ (r & 15)) * 8, smem + r * ROWB + HOFF);
      }
    }
    // ---- X-MFMA part 2 (covers stage-H round trip)
    #pragma unroll
    for (int i = XP1; i < XT; ++i) {
      const int px = ((t0x + i) * 2 + l5) ^ (r32 & 15);
      bf16x8 a0 = *(const bf16x8*)(smem + r32 * ROWB + px * 16);
      bf16x8 a1 = *(const bf16x8*)(smem + (32 + r32) * ROWB + px * 16);
      acc0 = __builtin_amdgcn_mfma_f32_32x32x16_bf16(a0, wfrag[i], acc0, 0, 0, 0);
      acc1 = __builtin_amdgcn_mfma_f32_32x32x16_bf16(a1, wfrag[i], acc1, 0, 0, 0);
    }
    __syncthreads();                   // (d) H staged + visible
    // ---- H-MFMA
    #pragma unroll
    for (int i = 0; i < HT; ++i) {
      const int px = ((t0h + i) * 2 + l5) ^ (r32 & 15);
      bf16x8 a0 = *(const bf16x8*)(smem + r32 * ROWB + px * 16);
      bf16x8 a1 = *(const bf16x8*)(smem + (32 + r32) * ROWB + px * 16);
      acc0 = __builtin_amdgcn_mfma_f32_32x32x16_bf16(a0, wfrag[XT + i], acc0, 0, 0, 0);
      acc1 = __builtin_amdgcn_mfma_f32_32x32x16_bf16(a1, wfrag[XT + i], acc1, 0, 0, 0);
    }
    __syncthreads();                   // (e) all A-reads done: gp overlay safe
    // ---- write partials: D col=lane&31 (n), row=(reg&3)+8*(reg>>2)+4*l5 (m)
    {
      const int base = kh * 8192 + g * 32 + r32;
      #pragma unroll
      for (int reg = 0; reg < 16; ++reg) {
        int mr = (reg & 3) + 8 * (reg >> 2) + 4 * l5;
        gp[base + mr * 128]        = acc0[reg];
        gp[base + (32 + mr) * 128] = acc1[reg];
      }
    }
    __syncthreads();                   // (f)
    // ---- lane-local c/h update (sum the 2 K-half partials)
    union { bf16x4 v; unsigned long long u; } pk;
    f32x4 hvf;
    {
      f32x4 gv[4];
      #pragma unroll
      for (int g2 = 0; g2 < 4; ++g2) {
        f32x4 p0 = *(const f32x4*)&gp[um * 128 + g2 * 32 + uq * 4];
        f32x4 p1 = *(const f32x4*)&gp[8192 + um * 128 + g2 * 32 + uq * 4];
        #pragma unroll
        for (int q = 0; q < 4; ++q) gv[g2][q] = p0[q] + p1[q];
      }
      #pragma unroll
      for (int q = 0; q < 4; ++q) {
        float i_ = gv[0][q] + bsv[0][q];
        float f_ = gv[1][q] + bsv[1][q];
        float g_ = gv[2][q] + bsv[2][q];
        float o_ = gv[3][q] + bsv[3][q];
        float si = 1.f / (1.f + __expf(-i_));
        float sf = 1.f / (1.f + __expf(-f_));
        float so = 1.f / (1.f + __expf(-o_));
        float tg = 2.f / (1.f + __expf(-2.f * g_)) - 1.f;
        float cv = sf * cst[q] + si * tg;
        cst[q] = cv;
        float th = 2.f / (1.f + __expf(-2.f * cv)) - 1.f;
        hvf[q] = so * th;
        pk.v[q] = (bf16_t)hvf[q];
      }
    }
    // ---- publish h at the MALL (atomic RMW executes/allocates at MALL)
    {
      int b = bg * 64 + um;
      bf16_t* dst = ringOwn + (size_t)slot * (256 * 512) + (size_t)b * 512 + u0 + uq * 4;
      (void)__hip_atomic_exchange((unsigned long long*)dst, pk.u,
                                  __ATOMIC_RELAXED, __HIP_MEMORY_SCOPE_AGENT);
      if (layer == 2 && s == 511)
        *(f32x4*)(hsf + (size_t)b * 512 + u0 + uq * 4) = hvf;
    }
    __syncthreads();                   // (g) vmcnt(0): h-swaps acked at MALL
    if (tid == 0)
      atomicAdd(fl_own + s * 4 * FSTR, 1);   // fire-and-forget
  }
}

__global__ __launch_bounds__(512, 2)
void lstm_persist(const bf16_t* __restrict__ xbf, const bf16_t* __restrict__ wc,
                  const float* __restrict__ bias, bf16_t* __restrict__ rings,
                  float* __restrict__ hsf, int* __restrict__ flags)
{
  __shared__ __align__(16) char smem[131072];
  const int bid   = blockIdx.x;
  const int layer = bid >> 6;
  const int bg    = (bid >> 4) & 3;
  const int ug    = bid & 15;
  bf16_t* ringOwn  = rings + (size_t)layer * RING_N;
  bf16_t* ringPrev = rings + (size_t)(layer - 1) * RING_N;  // unused for layer0
  if (layer == 0) {
    step_loop<true>(smem, xbf, wc, bias, ringPrev, ringOwn, hsf, flags, 0, bg, ug);
  } else {
    const bf16_t* wcl = wc + 2048 * 640 + (size_t)(layer - 1) * 2048 * 1024;
    step_loop<false>(smem, xbf, wcl, bias + layer * 2048, ringPrev, ringOwn, hsf,
                     flags, layer, bg, ug);
  }
}

// ---------------- final FC ----------------
__global__ void fc_kernel(const float* __restrict__ h, const float* __restrict__ Wfc,
                          const float* __restrict__ bfc, float* __restrict__ out) {
  int b = blockIdx.x;
  int l = threadIdx.x;
  const float* hp = h + (size_t)b * H_;
  float acc = 0.f;
  #pragma unroll
  for (int i = 0; i < 8; ++i) acc += hp[l + i * 64] * Wfc[l + i * 64];
  #pragma unroll
  for (int off = 32; off; off >>= 1) acc += __shfl_down(acc, off, 64);
  if (l == 0) out[b] = acc + bfc[0];
}

// ---------------- host ----------------
extern "C" void kernel_launch(void* const* d_in, const int* in_sizes, int n_in,
                              void* d_out, int out_size, void* d_ws, size_t ws_size,
                              hipStream_t stream) {
  const float* x        = (const float*)d_in[0];
  const float* Wih_f[3] = {(const float*)d_in[1], (const float*)d_in[5], (const float*)d_in[9]};
  const float* Whh_f[3] = {(const float*)d_in[2], (const float*)d_in[6], (const float*)d_in[10]};
  const float* bih_f[3] = {(const float*)d_in[3], (const float*)d_in[7], (const float*)d_in[11]};
  const float* bhh_f[3] = {(const float*)d_in[4], (const float*)d_in[8], (const float*)d_in[12]};
  const float* Wfc = (const float*)d_in[13];
  const float* bfc = (const float*)d_in[14];

  char* ws = (char*)d_ws;
  size_t off = 0;
  auto take = [&](size_t bytes) { char* p = ws + off; off = (off + bytes + 255) & ~255ULL; return p; };
  bf16_t* XBF   = (bf16_t*)take((size_t)B_ * T_ * DIN_ * 2);        // 33.6 MB
  bf16_t* WC    = (bf16_t*)take((size_t)(2048*640 + 2*2048*1024) * 2); // 11.0 MB
  float*  BIAS  = (float*) take(3 * 2048 * 4);
  bf16_t* RINGS = (bf16_t*)take((size_t)3 * RING_N * 2);            // 6.3 MB
  float*  HSF   = (float*) take((size_t)B_ * H_ * 4);
  int*    FLAGS = (int*)   take(3 * 512 * 4 * FSTR * 4);            // 64B/flag

  bf16_t* WC1 = WC + 2048 * 640;
  bf16_t* WC2 = WC1 + 2048 * 1024;

  // weights / x prep
  cast_f32_bf16<<<16384, 256, 0, stream>>>(x, XBF, B_ * T_ * DIN_);
  cast_strided<<<128, 256, 0, stream>>>(Wih_f[0], WC,  128, 640, 0);
  cast_strided<<<512, 256, 0, stream>>>(Whh_f[0], WC,  512, 640, 128);
  cast_strided<<<512, 256, 0, stream>>>(Wih_f[1], WC1, 512, 1024, 0);
  cast_strided<<<512, 256, 0, stream>>>(Whh_f[1], WC1, 512, 1024, 512);
  cast_strided<<<512, 256, 0, stream>>>(Wih_f[2], WC2, 512, 1024, 0);
  cast_strided<<<512, 256, 0, stream>>>(Whh_f[2], WC2, 512, 1024, 512);
  for (int l = 0; l < 3; ++l)
    bias_sum<<<8, 256, 0, stream>>>(bih_f[l], bhh_f[l], BIAS + l * 2048, G4_);
  hipMemsetAsync(RINGS, 0, (size_t)3 * RING_N * 2, stream);
  hipMemsetAsync(FLAGS, 0, 3 * 512 * 4 * FSTR * 4, stream);

  lstm_persist<<<192, 512, 0, stream>>>(XBF, WC, BIAS, RINGS, HSF, FLAGS);
  fc_kernel<<<B_, 64, 0, stream>>>(HSF, Wfc, bfc, (float*)d_out);
}

// Round 15
// 3279.068 us; speedup vs baseline: 1.5268x; 1.1339x over previous
//
#include <hip/hip_runtime.h>

#define B_   256
#define T_   512
#define DIN_ 128
#define H_   512
#define G4_  2048

typedef __bf16 bf16_t;
typedef __bf16 bf16x8 __attribute__((ext_vector_type(8)));
typedef __bf16 bf16x4 __attribute__((ext_vector_type(4)));
typedef float  f32x4  __attribute__((ext_vector_type(4)));
typedef float  f32x16 __attribute__((ext_vector_type(16)));

// coherent-point read (sc0|sc1 = 1|16): bypass L1+L2, read the MALL
__device__ __forceinline__ void gload16cc(const void* g, void* l) {
  __builtin_amdgcn_global_load_lds(
      (const __attribute__((address_space(1))) unsigned int*)g,
      (__attribute__((address_space(3))) unsigned int*)l, 16, 0, 17);
}

// ---------------- prep ----------------
__global__ void cast_f32_bf16(const float* __restrict__ s, bf16_t* __restrict__ d, int n) {
  int i = (blockIdx.x * 256 + threadIdx.x) * 4;
  if (i >= n) return;
  float4 v = *(const float4*)(s + i);
  bf16x4 o;
  o[0] = (bf16_t)v.x; o[1] = (bf16_t)v.y; o[2] = (bf16_t)v.z; o[3] = (bf16_t)v.w;
  *(bf16x4*)(d + i) = o;
}

// src f32 [2048][Ks] -> dst bf16 rows stride Kd at col offset coff
__global__ void cast_strided(const float* __restrict__ s, bf16_t* __restrict__ d,
                             int Ks, int Kd, int coff) {
  int npr = Ks >> 3;
  int i = blockIdx.x * 256 + threadIdx.x;
  if (i >= 2048 * npr) return;
  int row = i / npr, j = i - row * npr;
  const float* sp = s + (size_t)row * Ks + j * 8;
  float4 v0 = *(const float4*)sp;
  float4 v1 = *(const float4*)(sp + 4);
  bf16x8 o;
  o[0] = (bf16_t)v0.x; o[1] = (bf16_t)v0.y; o[2] = (bf16_t)v0.z; o[3] = (bf16_t)v0.w;
  o[4] = (bf16_t)v1.x; o[5] = (bf16_t)v1.y; o[6] = (bf16_t)v1.z; o[7] = (bf16_t)v1.w;
  *(bf16x8*)(d + (size_t)row * Kd + coff + j * 8) = o;
}

__global__ void bias_sum(const float* __restrict__ a, const float* __restrict__ b,
                         float* __restrict__ o, int n) {
  int i = blockIdx.x * 256 + threadIdx.x;
  if (i < n) o[i] = a[i] + b[i];
}

// ---------------- persistent 3-layer LSTM ----------------
// Final structure (round-10 best): 192 blocks = 3 layers x 4 bg x 16 ug;
// 8 waves = 4 gates x 2 K-halves; MFMA 32x32x16; W register-resident;
// MALL coherence via atomic publish + sc0|sc1 DMA reads; 64B-padded flags;
// two-phase step with mid-phase stage-H issue covered by X-MFMA part 2.
#define RING_N (8 * 256 * 512)
#define FSTR   16   // ints per flag (64B line)

template<bool L0>
__device__ __forceinline__ void step_loop(
    char* smem, const bf16_t* __restrict__ xbf, const bf16_t* __restrict__ wcl,
    const float* __restrict__ bias_l, bf16_t* ringPrev, bf16_t* ringOwn,
    float* __restrict__ hsf, int* flags, int layer, int bg, int ug)
{
  constexpr int KL   = L0 ? 640 : 1024;
  constexpr int ROWB = KL * 2;          // LDS row bytes
  constexpr int XT   = L0 ? 4 : 16;     // X-phase k-tiles(16) per wave
  constexpr int HT   = 16;              // H-phase k-tiles per wave
  constexpr int XP1  = L0 ? 2 : 8;      // X-MFMA tiles before stage-H issue
  constexpr int HOFF = L0 ? 256 : 1024; // byte offset of H region in a row
  const int tid  = threadIdx.x;
  const int lane = tid & 63;
  const int wv   = tid >> 6;
  const int g    = wv & 3;              // gate 0..3 (i,f,g,o)
  const int kh   = wv >> 2;             // K-half 0/1
  const int r32  = lane & 31;
  const int l5   = lane >> 5;
  const int u0   = ug * 32;
  const int t0x  = L0 ? (kh * 4) : (kh * 16);
  const int t0h  = L0 ? (8 + kh * 16) : (32 + kh * 16);

  // W fragments: lane holds W[g*512+u0+r32][tile*16 + l5*8 ..+8]
  bf16x8 wfrag[XT + HT];
  {
    const bf16_t* wrow = wcl + (size_t)(g * 512 + u0 + r32) * KL + l5 * 8;
    #pragma unroll
    for (int i = 0; i < XT; ++i) wfrag[i]      = *(const bf16x8*)(wrow + (t0x + i) * 16);
    #pragma unroll
    for (int i = 0; i < HT; ++i) wfrag[XT + i] = *(const bf16x8*)(wrow + (t0h + i) * 16);
  }
  const int um = tid >> 3;
  const int uq = tid & 7;
  float bsv[4][4];
  #pragma unroll
  for (int g2 = 0; g2 < 4; ++g2)
    #pragma unroll
    for (int q = 0; q < 4; ++q)
      bsv[g2][q] = bias_l[g2 * 512 + u0 + uq * 4 + q];

  float cst[4] = {0.f, 0.f, 0.f, 0.f};
  float* gp = (float*)smem;   // partials overlay: [2 kh][64 m][128 n] f32 = 64 KB

  int* fl_own  = flags + ((layer * 512) * 4 + bg) * FSTR;
  int* fl_prev = flags + (((layer - 1) * 512) * 4 + bg) * FSTR;
  int* fl_next = flags + (((layer + 1) * 512) * 4 + bg) * FSTR;

  for (int s = 0; s < 512; ++s) {
    const int slot  = s & 7;
    const int slot2 = (s - 1) & 7;
    // ================= Phase X: prev-layer input (no own-h dependency) =====
    if (!L0) {
      if (tid == 0)
        while (__hip_atomic_load(fl_prev + s * 4 * FSTR, __ATOMIC_RELAXED,
                                 __HIP_MEMORY_SCOPE_AGENT) < 16)
          __builtin_amdgcn_s_sleep(1);
      __syncthreads();                 // (a) flag visible; gp reads of s-1 done
      const bf16_t* prvS = ringPrev + (size_t)slot * (256 * 512) + (size_t)(bg * 64) * 512;
      #pragma unroll
      for (int i = 0; i < 8; ++i) {    // X region: chunks 0..63
        int r = i * 8 + wv;
        gload16cc(prvS + r * 512 + (lane ^ (r & 15)) * 8, smem + r * ROWB);
      }
    } else {
      #pragma unroll
      for (int i2 = 0; i2 < 2; ++i2) { // x-part: chunks 0..15 via regs
        int idx = i2 * 512 + tid;
        int r = idx >> 4, cx = idx & 15;
        int px = cx ^ (r & 15);
        bf16x8 v = *(const bf16x8*)(xbf + ((size_t)(bg * 64 + r) * T_ + s) * 128 + cx * 8);
        *(bf16x8*)(smem + r * ROWB + px * 16) = v;
      }
    }
    __syncthreads();                   // (b) X staged
    f32x16 acc0 = {}, acc1 = {};
    // ---- X-MFMA part 1
    #pragma unroll
    for (int i = 0; i < XP1; ++i) {
      const int px = ((t0x + i) * 2 + l5) ^ (r32 & 15);
      bf16x8 a0 = *(const bf16x8*)(smem + r32 * ROWB + px * 16);
      bf16x8 a1 = *(const bf16x8*)(smem + (32 + r32) * ROWB + px * 16);
      acc0 = __builtin_amdgcn_mfma_f32_32x32x16_bf16(a0, wfrag[i], acc0, 0, 0, 0);
      acc1 = __builtin_amdgcn_mfma_f32_32x32x16_bf16(a1, wfrag[i], acc1, 0, 0, 0);
    }
    // ---- own/next polls + stage-H issue (RT covered by X-part2)
    if (tid == 0) {
      if (s > 0)
        while (__hip_atomic_load(fl_own + (s - 1) * 4 * FSTR, __ATOMIC_RELAXED,
                                 __HIP_MEMORY_SCOPE_AGENT) < 16)
          __builtin_amdgcn_s_sleep(1);
      if (layer < 2 && s >= 8)         // ring back-pressure (depth 8)
        while (__hip_atomic_load(fl_next + (s - 8) * 4 * FSTR, __ATOMIC_RELAXED,
                                 __HIP_MEMORY_SCOPE_AGENT) < 16)
          __builtin_amdgcn_s_sleep(1);
    }
    __syncthreads();                   // (c) own flag seen by all
    {
      const bf16_t* ownS = ringOwn + (size_t)slot2 * (256 * 512) + (size_t)(bg * 64) * 512;
      #pragma unroll
      for (int i = 0; i < 8; ++i) {    // H region
        int r = i * 8 + wv;
        gload16cc(ownS + r * 512 + (lane ^ (r & 15)) * 8, smem + r * ROWB + HOFF);
      }
    }
    // ---- X-MFMA part 2 (covers stage-H round trip)
    #pragma unroll
    for (int i = XP1; i < XT; ++i) {
      const int px = ((t0x + i) * 2 + l5) ^ (r32 & 15);
      bf16x8 a0 = *(const bf16x8*)(smem + r32 * ROWB + px * 16);
      bf16x8 a1 = *(const bf16x8*)(smem + (32 + r32) * ROWB + px * 16);
      acc0 = __builtin_amdgcn_mfma_f32_32x32x16_bf16(a0, wfrag[i], acc0, 0, 0, 0);
      acc1 = __builtin_amdgcn_mfma_f32_32x32x16_bf16(a1, wfrag[i], acc1, 0, 0, 0);
    }
    __syncthreads();                   // (d) H staged + visible
    // ---- H-MFMA
    #pragma unroll
    for (int i = 0; i < HT; ++i) {
      const int px = ((t0h + i) * 2 + l5) ^ (r32 & 15);
      bf16x8 a0 = *(const bf16x8*)(smem + r32 * ROWB + px * 16);
      bf16x8 a1 = *(const bf16x8*)(smem + (32 + r32) * ROWB + px * 16);
      acc0 = __builtin_amdgcn_mfma_f32_32x32x16_bf16(a0, wfrag[XT + i], acc0, 0, 0, 0);
      acc1 = __builtin_amdgcn_mfma_f32_32x32x16_bf16(a1, wfrag[XT + i], acc1, 0, 0, 0);
    }
    __syncthreads();                   // (e) all A-reads done: gp overlay safe
    // ---- write partials: D col=lane&31 (n), row=(reg&3)+8*(reg>>2)+4*l5 (m)
    {
      const int base = kh * 8192 + g * 32 + r32;
      #pragma unroll
      for (int reg = 0; reg < 16; ++reg) {
        int mr = (reg & 3) + 8 * (reg >> 2) + 4 * l5;
        gp[base + mr * 128]        = acc0[reg];
        gp[base + (32 + mr) * 128] = acc1[reg];
      }
    }
    __syncthreads();                   // (f)
    // ---- lane-local c/h update (sum the 2 K-half partials)
    union { bf16x4 v; unsigned long long u; } pk;
    f32x4 hvf;
    {
      f32x4 gv[4];
      #pragma unroll
      for (int g2 = 0; g2 < 4; ++g2) {
        f32x4 p0 = *(const f32x4*)&gp[um * 128 + g2 * 32 + uq * 4];
        f32x4 p1 = *(const f32x4*)&gp[8192 + um * 128 + g2 * 32 + uq * 4];
        #pragma unroll
        for (int q = 0; q < 4; ++q) gv[g2][q] = p0[q] + p1[q];
      }
      #pragma unroll
      for (int q = 0; q < 4; ++q) {
        float i_ = gv[0][q] + bsv[0][q];
        float f_ = gv[1][q] + bsv[1][q];
        float g_ = gv[2][q] + bsv[2][q];
        float o_ = gv[3][q] + bsv[3][q];
        float si = 1.f / (1.f + __expf(-i_));
        float sf = 1.f / (1.f + __expf(-f_));
        float so = 1.f / (1.f + __expf(-o_));
        float tg = 2.f / (1.f + __expf(-2.f * g_)) - 1.f;
        float cv = sf * cst[q] + si * tg;
        cst[q] = cv;
        float th = 2.f / (1.f + __expf(-2.f * cv)) - 1.f;
        hvf[q] = so * th;
        pk.v[q] = (bf16_t)hvf[q];
      }
    }
    // ---- publish h at the MALL (atomic RMW executes/allocates at MALL)
    {
      int b = bg * 64 + um;
      bf16_t* dst = ringOwn + (size_t)slot * (256 * 512) + (size_t)b * 512 + u0 + uq * 4;
      (void)__hip_atomic_exchange((unsigned long long*)dst, pk.u,
                                  __ATOMIC_RELAXED, __HIP_MEMORY_SCOPE_AGENT);
      if (layer == 2 && s == 511)
        *(f32x4*)(hsf + (size_t)b * 512 + u0 + uq * 4) = hvf;
    }
    __syncthreads();                   // (g) vmcnt(0): h-swaps acked at MALL
    if (tid == 0)
      atomicAdd(fl_own + s * 4 * FSTR, 1);   // fire-and-forget
  }
}

__global__ __launch_bounds__(512, 2)
void lstm_persist(const bf16_t* __restrict__ xbf, const bf16_t* __restrict__ wc,
                  const float* __restrict__ bias, bf16_t* __restrict__ rings,
                  float* __restrict__ hsf, int* __restrict__ flags)
{
  __shared__ __align__(16) char smem[131072];
  const int bid   = blockIdx.x;
  const int layer = bid >> 6;
  const int bg    = (bid >> 4) & 3;
  const int ug    = bid & 15;
  bf16_t* ringOwn  = rings + (size_t)layer * RING_N;
  bf16_t* ringPrev = rings + (size_t)(layer - 1) * RING_N;  // unused for layer0
  if (layer == 0) {
    step_loop<true>(smem, xbf, wc, bias, ringPrev, ringOwn, hsf, flags, 0, bg, ug);
  } else {
    const bf16_t* wcl = wc + 2048 * 640 + (size_t)(layer - 1) * 2048 * 1024;
    step_loop<false>(smem, xbf, wcl, bias + layer * 2048, ringPrev, ringOwn, hsf,
                     flags, layer, bg, ug);
  }
}

// ---------------- final FC ----------------
__global__ void fc_kernel(const float* __restrict__ h, const float* __restrict__ Wfc,
                          const float* __restrict__ bfc, float* __restrict__ out) {
  int b = blockIdx.x;
  int l = threadIdx.x;
  const float* hp = h + (size_t)b * H_;
  float acc = 0.f;
  #pragma unroll
  for (int i = 0; i < 8; ++i) acc += hp[l + i * 64] * Wfc[l + i * 64];
  #pragma unroll
  for (int off = 32; off; off >>= 1) acc += __shfl_down(acc, off, 64);
  if (l == 0) out[b] = acc + bfc[0];
}

// ---------------- host ----------------
extern "C" void kernel_launch(void* const* d_in, const int* in_sizes, int n_in,
                              void* d_out, int out_size, void* d_ws, size_t ws_size,
                              hipStream_t stream) {
  const float* x        = (const float*)d_in[0];
  const float* Wih_f[3] = {(const float*)d_in[1], (const float*)d_in[5], (const float*)d_in[9]};
  const float* Whh_f[3] = {(const float*)d_in[2], (const float*)d_in[6], (const float*)d_in[10]};
  const float* bih_f[3] = {(const float*)d_in[3], (const float*)d_in[7], (const float*)d_in[11]};
  const float* bhh_f[3] = {(const float*)d_in[4], (const float*)d_in[8], (const float*)d_in[12]};
  const float* Wfc = (const float*)d_in[13];
  const float* bfc = (const float*)d_in[14];

  char* ws = (char*)d_ws;
  size_t off = 0;
  auto take = [&](size_t bytes) { char* p = ws + off; off = (off + bytes + 255) & ~255ULL; return p; };
  bf16_t* XBF   = (bf16_t*)take((size_t)B_ * T_ * DIN_ * 2);        // 33.6 MB
  bf16_t* WC    = (bf16_t*)take((size_t)(2048*640 + 2*2048*1024) * 2); // 11.0 MB
  float*  BIAS  = (float*) take(3 * 2048 * 4);
  bf16_t* RINGS = (bf16_t*)take((size_t)3 * RING_N * 2);            // 6.3 MB
  float*  HSF   = (float*) take((size_t)B_ * H_ * 4);
  int*    FLAGS = (int*)   take(3 * 512 * 4 * FSTR * 4);            // 64B/flag

  bf16_t* WC1 = WC + 2048 * 640;
  bf16_t* WC2 = WC1 + 2048 * 1024;

  // weights / x prep
  cast_f32_bf16<<<16384, 256, 0, stream>>>(x, XBF, B_ * T_ * DIN_);
  cast_strided<<<128, 256, 0, stream>>>(Wih_f[0], WC,  128, 640, 0);
  cast_strided<<<512, 256, 0, stream>>>(Whh_f[0], WC,  512, 640, 128);
  cast_strided<<<512, 256, 0, stream>>>(Wih_f[1], WC1, 512, 1024, 0);
  cast_strided<<<512, 256, 0, stream>>>(Whh_f[1], WC1, 512, 1024, 512);
  cast_strided<<<512, 256, 0, stream>>>(Wih_f[2], WC2, 512, 1024, 0);
  cast_strided<<<512, 256, 0, stream>>>(Whh_f[2], WC2, 512, 1024, 512);
  for (int l = 0; l < 3; ++l)
    bias_sum<<<8, 256, 0, stream>>>(bih_f[l], bhh_f[l], BIAS + l * 2048, G4_);
  hipMemsetAsync(RINGS, 0, (size_t)3 * RING_N * 2, stream);
  hipMemsetAsync(FLAGS, 0, 3 * 512 * 4 * FSTR * 4, stream);

  lstm_persist<<<192, 512, 0, stream>>>(XBF, WC, BIAS, RINGS, HSF, FLAGS);
  fc_kernel<<<B_, 64, 0, stream>>>(HSF, Wfc, bfc, (float*)d_out);
}